// Round 10
// baseline (2073.152 us; speedup 1.0000x reference)
//
#include <hip/hip_runtime.h>

#define NN 50000
#define NE 800000
#define HD 128
#define INN 11
#define NL 4
#define NG16 3125        // 16-row node groups
#define EW16 50000       // 16-edge wave-tasks (NE/16)
#define BTS 132          // LDS K stride (shorts): 66 dwords, gcd(66,32)=2 -> conflict-free
#define K1S 292          // nk1 K stride: 146 dwords, gcd(146,32)=2 -> conflict-free

typedef __attribute__((ext_vector_type(8))) short bf16x8;
typedef __attribute__((ext_vector_type(4))) float f32x4;

__device__ __forceinline__ float silu_f(float x) {
    return x * __builtin_amdgcn_rcpf(1.0f + __expf(-x));
}

__device__ __forceinline__ short f2bf(float x) {
    unsigned u = __float_as_uint(x);
    return (short)((u + 0x7FFFu + ((u >> 16) & 1u)) >> 16);
}
__device__ __forceinline__ float bf2f(short s) {
    return __uint_as_float(((unsigned)(unsigned short)s) << 16);
}
__device__ __forceinline__ bf16x8 pack8(float4 a, float4 b) {
    bf16x8 r;
    r[0] = f2bf(a.x); r[1] = f2bf(a.y); r[2] = f2bf(a.z); r[3] = f2bf(a.w);
    r[4] = f2bf(b.x); r[5] = f2bf(b.y); r[6] = f2bf(b.z); r[7] = f2bf(b.w);
    return r;
}

// ---------------- zero agg ----------------
__global__ __launch_bounds__(256) void zero_kernel(float4* __restrict__ p, int n4)
{
    int i = blockIdx.x * 256 + threadIdx.x;
    if (i < n4) p[i] = make_float4(0.f, 0.f, 0.f, 0.f);
}

// ---------------- embedding ----------------
__global__ __launch_bounds__(256) void embed_kernel(
    const float* __restrict__ h0, const float* __restrict__ w,
    const float* __restrict__ b, float* __restrict__ h)
{
    int idx = blockIdx.x * 256 + threadIdx.x;
    if (idx >= NN * HD) return;
    int n = idx >> 7, j = idx & 127;
    float acc = b[j];
    #pragma unroll
    for (int k = 0; k < INN; ++k)
        acc += h0[n * INN + k] * w[k * HD + j];
    h[idx] = acc;
}

// ---------------- CSR build ----------------
__global__ __launch_bounds__(256) void csr_zero(int* __restrict__ cnt)
{
    int i = blockIdx.x * 256 + threadIdx.x;
    if (i < NN) cnt[i] = 0;
}

__global__ __launch_bounds__(256) void csr_hist(const int* __restrict__ ei, int* __restrict__ cnt)
{
    int e = blockIdx.x * 256 + threadIdx.x;
    atomicAdd(&cnt[ei[e]], 1);
}

__global__ __launch_bounds__(1024) void csr_scan(
    const int* __restrict__ cnt, int* __restrict__ rowptr, int* __restrict__ cursor)
{
    __shared__ int part[1024];
    int t = threadIdx.x;
    int base = t * 49;
    int s = 0;
    for (int i = 0; i < 49; ++i) { int j = base + i; if (j < NN) s += cnt[j]; }
    part[t] = s;
    __syncthreads();
    for (int off = 1; off < 1024; off <<= 1) {
        int v = (t >= off) ? part[t - off] : 0;
        __syncthreads();
        part[t] += v;
        __syncthreads();
    }
    int run = (t == 0) ? 0 : part[t - 1];
    for (int i = 0; i < 49; ++i) {
        int j = base + i;
        if (j < NN) { rowptr[j] = run; cursor[j] = run; run += cnt[j]; }
    }
    if (t == 1023) rowptr[NN] = part[1023];
}

__global__ __launch_bounds__(256) void csr_fill(
    const int* __restrict__ ei, int* __restrict__ cursor, int* __restrict__ eidx)
{
    int e = blockIdx.x * 256 + threadIdx.x;
    int r = ei[e];
    int p = atomicAdd(&cursor[r], 1);
    eidx[p] = e;
}

// ---------------- per-edge data, permuted to CSR order; rc pre-scaled by 64 ----------------
__global__ __launch_bounds__(256) void edge_pre(
    const int* __restrict__ ei, const int* __restrict__ eidx,
    const float* __restrict__ x, const float* __restrict__ eattr,
    const float* __restrict__ emask,
    int2* __restrict__ rc_p, float2* __restrict__ rm_p, float4* __restrict__ ea_p)
{
    int p = blockIdx.x * 256 + threadIdx.x;
    int e = eidx[p];
    int r = ei[e], c = ei[NE + e];
    rc_p[p] = make_int2(r * 64, c * 64);   // dword offsets into tb/ub
    float dx = x[3 * r]     - x[3 * c];
    float dy = x[3 * r + 1] - x[3 * c + 1];
    float dz = x[3 * r + 2] - x[3 * c + 2];
    rm_p[p] = make_float2(dx * dx + dy * dy + dz * dz, emask[e]);
    ea_p[p] = ((const float4*)eattr)[e];
}

// ---------------- t|u = h @ ew1 halves (persistent MFMA, bf16 out) ----------------
__global__ __launch_bounds__(512) void tu_mfma(
    const float* __restrict__ h, const float* __restrict__ ew1_l,
    short* __restrict__ tb, short* __restrict__ ub)
{
    __shared__ __align__(16) short BT[128 * BTS];
    const float* wsrc = ew1_l + (blockIdx.y ? 128 * HD : 0);
    short* outp = blockIdx.y ? ub : tb;
    for (int i = threadIdx.x; i < 128 * 128; i += 512) {
        int c = i >> 7, k = i & 127;
        BT[c * BTS + k] = f2bf(wsrc[k * HD + c]);
    }
    int wv = threadIdx.x >> 6, lane = threadIdx.x & 63;
    int ln15 = lane & 15, quad = lane >> 4;
    __syncthreads();

    for (int g = blockIdx.x * 8 + wv; g < NG16; g += gridDim.x * 8) {
        int row = g * 16 + ln15;
        const float* hrow = h + row * HD;
        bf16x8 afr[4];
        #pragma unroll
        for (int kt = 0; kt < 4; ++kt) {
            float4 x0 = *(const float4*)(hrow + kt * 32 + quad * 8);
            float4 x1 = *(const float4*)(hrow + kt * 32 + quad * 8 + 4);
            afr[kt] = pack8(x0, x1);
        }
        #pragma unroll
        for (int ct = 0; ct < 8; ++ct) {
            f32x4 acc = {0.f, 0.f, 0.f, 0.f};
            #pragma unroll
            for (int kt = 0; kt < 4; ++kt) {
                bf16x8 bfr = *(const bf16x8*)&BT[(ct * 16 + ln15) * BTS + kt * 32 + quad * 8];
                acc = __builtin_amdgcn_mfma_f32_16x16x32_bf16(afr[kt], bfr, acc, 0, 0, 0);
            }
            int col = ct * 16 + ln15;
            #pragma unroll
            for (int r4 = 0; r4 < 4; ++r4) {
                int orow = g * 16 + quad * 4 + r4;
                outp[orow * HD + col] = f2bf(acc[r4]);
            }
        }
    }
}

// ---------------- wave-autonomous fused edge model: register A-frags, no LDS transpose ----
// lane = (edge ln15, col-group quad); each lane computes its edge's 32 cols directly in
// A-frag layout [m=ln15][k=quad*8+j + kt*32]. Barrier-free task loop.
__global__ __launch_bounds__(256) void edge_m_kernel(
    const short* __restrict__ tb, const short* __restrict__ ub,
    const int2* __restrict__ rc_p, const float2* __restrict__ rm_p,
    const float4* __restrict__ ea_p,
    const float* __restrict__ ew1_l, const float* __restrict__ eb1_l,
    const float* __restrict__ ew2_l, const float* __restrict__ eb2_l,
    float* __restrict__ agg)
{
    __shared__ __align__(16) short BT[128 * BTS];   // 33792 B
    __shared__ __align__(16) float TW[6][128];      // wr, wa0..3, b1  (3072 B)
    __shared__ float s_b2[128];                     // 512 B   -> total 37376 B (4 blocks/CU)

    for (int i = threadIdx.x; i < 128 * 128; i += 256) {
        int k = i >> 7, n = i & 127;
        BT[n * BTS + k] = f2bf(ew2_l[i]);
    }
    for (int i = threadIdx.x; i < 5 * 128; i += 256)
        TW[0][i] = ew1_l[256 * HD + i];             // rows 256..260 are contiguous
    if (threadIdx.x < 128) {
        TW[5][threadIdx.x] = eb1_l[threadIdx.x];
        s_b2[threadIdx.x]  = eb2_l[threadIdx.x];
    }

    int lane = threadIdx.x & 63;
    int wv   = threadIdx.x >> 6;
    int ln15 = lane & 15;
    int quad = lane >> 4;
    __syncthreads();

    for (int gw = blockIdx.x * 4 + wv; gw < EW16; gw += gridDim.x * 4) {
        // ---- v-phase: this lane's edge, 32 cols in A-frag layout
        int p = gw * 16 + ln15;
        int2   rc = rc_p[p];
        float2 rm = rm_p[p];
        float4 ea = ea_p[p];
        const short* trow = tb + rc.x * 2;
        const short* urow = ub + rc.y * 2;
        bf16x8 afr[4];
        #pragma unroll
        for (int kt = 0; kt < 4; ++kt) {
            int coff = kt * 32 + quad * 8;
            bf16x8 tv = *(const bf16x8*)(trow + coff);
            bf16x8 uv = *(const bf16x8*)(urow + coff);
            float4 wr0  = *(const float4*)&TW[0][coff];
            float4 wr1  = *(const float4*)&TW[0][coff + 4];
            float4 wa00 = *(const float4*)&TW[1][coff];
            float4 wa01 = *(const float4*)&TW[1][coff + 4];
            float4 wa10 = *(const float4*)&TW[2][coff];
            float4 wa11 = *(const float4*)&TW[2][coff + 4];
            float4 wa20 = *(const float4*)&TW[3][coff];
            float4 wa21 = *(const float4*)&TW[3][coff + 4];
            float4 wa30 = *(const float4*)&TW[4][coff];
            float4 wa31 = *(const float4*)&TW[4][coff + 4];
            float4 b10  = *(const float4*)&TW[5][coff];
            float4 b11  = *(const float4*)&TW[5][coff + 4];
            float pre[8];
            pre[0] = b10.x + rm.x * wr0.x + ea.x * wa00.x + ea.y * wa10.x + ea.z * wa20.x + ea.w * wa30.x;
            pre[1] = b10.y + rm.x * wr0.y + ea.x * wa00.y + ea.y * wa10.y + ea.z * wa20.y + ea.w * wa30.y;
            pre[2] = b10.z + rm.x * wr0.z + ea.x * wa00.z + ea.y * wa10.z + ea.z * wa20.z + ea.w * wa30.z;
            pre[3] = b10.w + rm.x * wr0.w + ea.x * wa00.w + ea.y * wa10.w + ea.z * wa20.w + ea.w * wa30.w;
            pre[4] = b11.x + rm.x * wr1.x + ea.x * wa01.x + ea.y * wa11.x + ea.z * wa21.x + ea.w * wa31.x;
            pre[5] = b11.y + rm.x * wr1.y + ea.x * wa01.y + ea.y * wa11.y + ea.z * wa21.y + ea.w * wa31.y;
            pre[6] = b11.z + rm.x * wr1.z + ea.x * wa01.z + ea.y * wa11.z + ea.z * wa21.z + ea.w * wa31.z;
            pre[7] = b11.w + rm.x * wr1.w + ea.x * wa01.w + ea.y * wa11.w + ea.z * wa21.w + ea.w * wa31.w;
            bf16x8 o;
            #pragma unroll
            for (int j = 0; j < 8; ++j)
                o[j] = f2bf(silu_f(pre[j] + bf2f(tv[j]) + bf2f(uv[j])));
            afr[kt] = o;
        }

        // epilogue edge metadata for this wave's 16 edges (quad owns 4 consecutive)
        int em0 = gw * 16 + quad * 4;
        int   r0 = rc_p[em0 + 0].x, r1 = rc_p[em0 + 1].x;   // scaled by 64
        int   r2 = rc_p[em0 + 2].x, r3 = rc_p[em0 + 3].x;
        float mk0 = rm_p[em0 + 0].y, mk1 = rm_p[em0 + 1].y;
        float mk2 = rm_p[em0 + 2].y, mk3 = rm_p[em0 + 3].y;

        #pragma unroll
        for (int ct = 0; ct < 8; ++ct) {
            f32x4 acc = {0.f, 0.f, 0.f, 0.f};
            #pragma unroll
            for (int kt = 0; kt < 4; ++kt) {
                bf16x8 bfr = *(const bf16x8*)&BT[(ct * 16 + ln15) * BTS + kt * 32 + quad * 8];
                acc = __builtin_amdgcn_mfma_f32_16x16x32_bf16(afr[kt], bfr, acc, 0, 0, 0);
            }
            int col = ct * 16 + ln15;
            float b2c = s_b2[col];
            float m0 = silu_f(acc[0] + b2c) * mk0;
            float m1 = silu_f(acc[1] + b2c) * mk1;
            float m2 = silu_f(acc[2] + b2c) * mk2;
            float m3 = silu_f(acc[3] + b2c) * mk3;
            // run-length segmented flush (rows CSR-sorted); agg idx = r_scaled*2 + col
            float run = m0;
            int cur = r0;
            if (r1 != cur) { atomicAdd(&agg[cur * 2 + col], run); run = 0.f; cur = r1; }
            run += m1;
            if (r2 != cur) { atomicAdd(&agg[cur * 2 + col], run); run = 0.f; cur = r2; }
            run += m2;
            if (r3 != cur) { atomicAdd(&agg[cur * 2 + col], run); run = 0.f; cur = r3; }
            run += m3;
            atomicAdd(&agg[cur * 2 + col], run);
        }
    }
}

// ---------------- node MLP layer 1 (persistent MFMA) ----------------
__global__ __launch_bounds__(512) void nk1_mfma(
    const float* __restrict__ h, const float* __restrict__ agg,
    const float* __restrict__ h0,
    const float* __restrict__ nw1_l, const float* __restrict__ nb1_l,
    short* __restrict__ qb)
{
    __shared__ __align__(16) short BT[64 * K1S];
    int c0 = blockIdx.y * 64;
    for (int i = threadIdx.x; i < 64 * 288; i += 512) {
        int c = i / 288, k = i - c * 288;
        BT[c * K1S + k] = (k < 267) ? f2bf(nw1_l[k * HD + c0 + c]) : (short)0;
    }
    int wv = threadIdx.x >> 6, lane = threadIdx.x & 63;
    int ln15 = lane & 15, quad = lane >> 4;
    __syncthreads();

    for (int g = blockIdx.x * 8 + wv; g < NG16; g += gridDim.x * 8) {
        int row = g * 16 + ln15;
        const float* hrow = h + row * HD;
        const float* arow = agg + row * HD;
        bf16x8 afr[9];
        #pragma unroll
        for (int kt = 0; kt < 4; ++kt) {
            float4 x0 = *(const float4*)(hrow + kt * 32 + quad * 8);
            float4 x1 = *(const float4*)(hrow + kt * 32 + quad * 8 + 4);
            afr[kt] = pack8(x0, x1);
        }
        #pragma unroll
        for (int kt = 0; kt < 4; ++kt) {
            float4 x0 = *(const float4*)(arow + kt * 32 + quad * 8);
            float4 x1 = *(const float4*)(arow + kt * 32 + quad * 8 + 4);
            afr[4 + kt] = pack8(x0, x1);
        }
        {
            bf16x8 a8 = {0, 0, 0, 0, 0, 0, 0, 0};
            if (quad == 0) {
                #pragma unroll
                for (int jj = 0; jj < 8; ++jj) a8[jj] = f2bf(h0[row * INN + jj]);
            } else if (quad == 1) {
                #pragma unroll
                for (int jj = 0; jj < 3; ++jj) a8[jj] = f2bf(h0[row * INN + 8 + jj]);
            }
            afr[8] = a8;
        }
        #pragma unroll
        for (int ct = 0; ct < 4; ++ct) {
            f32x4 acc = {0.f, 0.f, 0.f, 0.f};
            #pragma unroll
            for (int kt = 0; kt < 9; ++kt) {
                bf16x8 bfr = *(const bf16x8*)&BT[(ct * 16 + ln15) * K1S + kt * 32 + quad * 8];
                acc = __builtin_amdgcn_mfma_f32_16x16x32_bf16(afr[kt], bfr, acc, 0, 0, 0);
            }
            int col = c0 + ct * 16 + ln15;
            float b = nb1_l[col];
            #pragma unroll
            for (int r4 = 0; r4 < 4; ++r4) {
                int orow = g * 16 + quad * 4 + r4;
                qb[orow * HD + col] = f2bf(silu_f(acc[r4] + b));
            }
        }
    }
}

// ---------------- node MLP layer 2 + residual (persistent MFMA) ----------------
__global__ __launch_bounds__(512) void nk2_mfma(
    const short* __restrict__ qb, const float* __restrict__ nw2_l,
    const float* __restrict__ nb2_l, float* __restrict__ h)
{
    __shared__ __align__(16) short BT[128 * BTS];
    for (int i = threadIdx.x; i < 128 * 128; i += 512) {
        int c = i >> 7, k = i & 127;
        BT[c * BTS + k] = f2bf(nw2_l[k * HD + c]);
    }
    int wv = threadIdx.x >> 6, lane = threadIdx.x & 63;
    int ln15 = lane & 15, quad = lane >> 4;
    __syncthreads();

    for (int g = blockIdx.x * 8 + wv; g < NG16; g += gridDim.x * 8) {
        int row = g * 16 + ln15;
        bf16x8 afr[4];
        #pragma unroll
        for (int kt = 0; kt < 4; ++kt)
            afr[kt] = *(const bf16x8*)(qb + row * HD + kt * 32 + quad * 8);

        #pragma unroll
        for (int ct = 0; ct < 8; ++ct) {
            f32x4 acc = {0.f, 0.f, 0.f, 0.f};
            #pragma unroll
            for (int kt = 0; kt < 4; ++kt) {
                bf16x8 bfr = *(const bf16x8*)&BT[(ct * 16 + ln15) * BTS + kt * 32 + quad * 8];
                acc = __builtin_amdgcn_mfma_f32_16x16x32_bf16(afr[kt], bfr, acc, 0, 0, 0);
            }
            int col = ct * 16 + ln15;
            float b = nb2_l[col];
            #pragma unroll
            for (int r4 = 0; r4 < 4; ++r4) {
                int orow = g * 16 + quad * 4 + r4;
                h[orow * HD + col] += acc[r4] + b;
            }
        }
    }
}

extern "C" void kernel_launch(void* const* d_in, const int* in_sizes, int n_in,
                              void* d_out, int out_size, void* d_ws, size_t ws_size,
                              hipStream_t stream)
{
    const float* h0    = (const float*)d_in[0];
    const float* x     = (const float*)d_in[1];
    const int*   ei    = (const int*)d_in[2];
    const float* eattr = (const float*)d_in[3];
    const float* emask = (const float*)d_in[5];
    const float* emb_w = (const float*)d_in[7];
    const float* emb_b = (const float*)d_in[8];
    const float* ew1   = (const float*)d_in[9];
    const float* eb1   = (const float*)d_in[10];
    const float* ew2   = (const float*)d_in[11];
    const float* eb2   = (const float*)d_in[12];
    const float* nw1   = (const float*)d_in[13];
    const float* nb1   = (const float*)d_in[14];
    const float* nw2   = (const float*)d_in[15];
    const float* nb2   = (const float*)d_in[16];

    float* h = (float*)d_out;

    // workspace layout (~80.6 MB; d_ws >= 256 MiB)
    short*  tb     = (short*)d_ws;                         // NN*HD bf16
    short*  ub     = tb + (size_t)NN * HD;                 // NN*HD bf16
    float*  agg    = (float*)(ub + (size_t)NN * HD);       // NN*HD fp32
    short*  qb     = tb;                                   // alias (tb dead by nk1)
    int*    cnt    = (int*)(agg + (size_t)NN * HD);        // NN
    int*    rowptr = cnt + NN;                             // NN+1
    int*    cursor = rowptr + NN + 1;                      // NN
    int*    eidx   = cursor + NN;                          // NE
    int2*   rc_p   = (int2*)(eidx + NE);                   // NE int2
    float2* rm_p   = (float2*)(rc_p + NE);                 // NE float2
    float4* ea_p   = (float4*)(rm_p + NE);                 // NE float4

    csr_zero<<<(NN + 255) / 256, 256, 0, stream>>>(cnt);
    csr_hist<<<NE / 256, 256, 0, stream>>>(ei, cnt);
    csr_scan<<<1, 1024, 0, stream>>>(cnt, rowptr, cursor);
    csr_fill<<<NE / 256, 256, 0, stream>>>(ei, cursor, eidx);
    edge_pre<<<NE / 256, 256, 0, stream>>>(ei, eidx, x, eattr, emask, rc_p, rm_p, ea_p);

    embed_kernel<<<(NN * HD + 255) / 256, 256, 0, stream>>>(h0, emb_w, emb_b, h);

    dim3 gtu(128, 2);
    dim3 gn1(128, 2);
    for (int l = 0; l < NL; ++l) {
        tu_mfma<<<gtu, 512, 0, stream>>>(h, ew1 + l * 261 * HD, tb, ub);
        zero_kernel<<<(NN * HD / 4 + 255) / 256, 256, 0, stream>>>((float4*)agg, NN * HD / 4);
        edge_m_kernel<<<1024, 256, 0, stream>>>(tb, ub, rc_p, rm_p, ea_p,
            ew1 + l * 261 * HD, eb1 + l * HD, ew2 + l * HD * HD, eb2 + l * HD, agg);
        nk1_mfma<<<gn1, 512, 0, stream>>>(h, agg, h0,
            nw1 + l * 267 * HD, nb1 + l * HD, qb);
        nk2_mfma<<<128, 512, 0, stream>>>(qb, nw2 + l * HD * HD, nb2 + l * HD, h);
    }
}

// Round 11
// 1970.021 us; speedup vs baseline: 1.0524x; 1.0524x over previous
//
#include <hip/hip_runtime.h>

#define NN 50000
#define NE 800000
#define HD 128
#define INN 11
#define NL 4
#define NG16 3125        // 16-row node groups
#define EW16 50000       // 16-edge wave-tasks (NE/16)
#define BTS 132          // LDS K stride (shorts): empirically conflict-clean for this pattern
#define K1S 292          // nk1 K stride

typedef __attribute__((ext_vector_type(8))) short bf16x8;
typedef __attribute__((ext_vector_type(4))) float f32x4;

__device__ __forceinline__ float silu_f(float x) {
    return x * __builtin_amdgcn_rcpf(1.0f + __expf(-x));
}

__device__ __forceinline__ short f2bf(float x) {
    unsigned u = __float_as_uint(x);
    return (short)((u + 0x7FFFu + ((u >> 16) & 1u)) >> 16);
}
__device__ __forceinline__ unsigned f2bf2u(float lo, float hi) {
    unsigned a = __float_as_uint(lo), b = __float_as_uint(hi);
    a = (a + 0x7FFFu + ((a >> 16) & 1u)) >> 16;
    b = (b + 0x7FFFu + ((b >> 16) & 1u)) & 0xFFFF0000u;
    return a | b;
}
__device__ __forceinline__ bf16x8 pack8(float4 a, float4 b) {
    bf16x8 r;
    r[0] = f2bf(a.x); r[1] = f2bf(a.y); r[2] = f2bf(a.z); r[3] = f2bf(a.w);
    r[4] = f2bf(b.x); r[5] = f2bf(b.y); r[6] = f2bf(b.z); r[7] = f2bf(b.w);
    return r;
}

// ---------------- zero agg ----------------
__global__ __launch_bounds__(256) void zero_kernel(float4* __restrict__ p, int n4)
{
    int i = blockIdx.x * 256 + threadIdx.x;
    if (i < n4) p[i] = make_float4(0.f, 0.f, 0.f, 0.f);
}

// ---------------- embedding ----------------
__global__ __launch_bounds__(256) void embed_kernel(
    const float* __restrict__ h0, const float* __restrict__ w,
    const float* __restrict__ b, float* __restrict__ h)
{
    int idx = blockIdx.x * 256 + threadIdx.x;
    if (idx >= NN * HD) return;
    int n = idx >> 7, j = idx & 127;
    float acc = b[j];
    #pragma unroll
    for (int k = 0; k < INN; ++k)
        acc += h0[n * INN + k] * w[k * HD + j];
    h[idx] = acc;
}

// ---------------- CSR build ----------------
__global__ __launch_bounds__(256) void csr_zero(int* __restrict__ cnt)
{
    int i = blockIdx.x * 256 + threadIdx.x;
    if (i < NN) cnt[i] = 0;
}

__global__ __launch_bounds__(256) void csr_hist(const int* __restrict__ ei, int* __restrict__ cnt)
{
    int e = blockIdx.x * 256 + threadIdx.x;
    atomicAdd(&cnt[ei[e]], 1);
}

__global__ __launch_bounds__(1024) void csr_scan(
    const int* __restrict__ cnt, int* __restrict__ rowptr, int* __restrict__ cursor)
{
    __shared__ int part[1024];
    int t = threadIdx.x;
    int base = t * 49;
    int s = 0;
    for (int i = 0; i < 49; ++i) { int j = base + i; if (j < NN) s += cnt[j]; }
    part[t] = s;
    __syncthreads();
    for (int off = 1; off < 1024; off <<= 1) {
        int v = (t >= off) ? part[t - off] : 0;
        __syncthreads();
        part[t] += v;
        __syncthreads();
    }
    int run = (t == 0) ? 0 : part[t - 1];
    for (int i = 0; i < 49; ++i) {
        int j = base + i;
        if (j < NN) { rowptr[j] = run; cursor[j] = run; run += cnt[j]; }
    }
    if (t == 1023) rowptr[NN] = part[1023];
}

__global__ __launch_bounds__(256) void csr_fill(
    const int* __restrict__ ei, int* __restrict__ cursor, int* __restrict__ eidx)
{
    int e = blockIdx.x * 256 + threadIdx.x;
    int r = ei[e];
    int p = atomicAdd(&cursor[r], 1);
    eidx[p] = e;
}

// ---------------- per-edge data, CSR order; ed = {r*64, c*64, rad, mask} ----------------
__global__ __launch_bounds__(256) void edge_pre(
    const int* __restrict__ ei, const int* __restrict__ eidx,
    const float* __restrict__ x, const float* __restrict__ eattr,
    const float* __restrict__ emask,
    int4* __restrict__ ed_p, float4* __restrict__ ea_p)
{
    int p = blockIdx.x * 256 + threadIdx.x;
    int e = eidx[p];
    int r = ei[e], c = ei[NE + e];
    float dx = x[3 * r]     - x[3 * c];
    float dy = x[3 * r + 1] - x[3 * c + 1];
    float dz = x[3 * r + 2] - x[3 * c + 2];
    float rad = dx * dx + dy * dy + dz * dz;
    ed_p[p] = make_int4(r * 64, c * 64, __float_as_int(rad), __float_as_int(emask[e]));
    ea_p[p] = ((const float4*)eattr)[e];
}

// ---------------- t|u = h @ ew1 halves (persistent MFMA, bf16 out) ----------------
__global__ __launch_bounds__(512) void tu_mfma(
    const float* __restrict__ h, const float* __restrict__ ew1_l,
    short* __restrict__ tb, short* __restrict__ ub)
{
    __shared__ __align__(16) short BT[128 * BTS];
    const float* wsrc = ew1_l + (blockIdx.y ? 128 * HD : 0);
    short* outp = blockIdx.y ? ub : tb;
    for (int i = threadIdx.x; i < 128 * 128; i += 512) {
        int c = i >> 7, k = i & 127;
        BT[c * BTS + k] = f2bf(wsrc[k * HD + c]);
    }
    int wv = threadIdx.x >> 6, lane = threadIdx.x & 63;
    int ln15 = lane & 15, quad = lane >> 4;
    __syncthreads();

    for (int g = blockIdx.x * 8 + wv; g < NG16; g += gridDim.x * 8) {
        int row = g * 16 + ln15;
        const float* hrow = h + row * HD;
        bf16x8 afr[4];
        #pragma unroll
        for (int kt = 0; kt < 4; ++kt) {
            float4 x0 = *(const float4*)(hrow + kt * 32 + quad * 8);
            float4 x1 = *(const float4*)(hrow + kt * 32 + quad * 8 + 4);
            afr[kt] = pack8(x0, x1);
        }
        #pragma unroll
        for (int ct = 0; ct < 8; ++ct) {
            f32x4 acc = {0.f, 0.f, 0.f, 0.f};
            #pragma unroll
            for (int kt = 0; kt < 4; ++kt) {
                bf16x8 bfr = *(const bf16x8*)&BT[(ct * 16 + ln15) * BTS + kt * 32 + quad * 8];
                acc = __builtin_amdgcn_mfma_f32_16x16x32_bf16(afr[kt], bfr, acc, 0, 0, 0);
            }
            int col = ct * 16 + ln15;
            #pragma unroll
            for (int r4 = 0; r4 < 4; ++r4) {
                int orow = g * 16 + quad * 4 + r4;
                outp[orow * HD + col] = f2bf(acc[r4]);
            }
        }
    }
}

// ---------------- wave-autonomous fused edge model (shared BT, 8 waves/block) ----------------
// v-phase: lane = col-pair cp; 16 edges/task into this wave's private VA; MFMA; scatter.
__global__ __launch_bounds__(512) void edge_m_kernel(
    const short* __restrict__ tb, const short* __restrict__ ub,
    const int4* __restrict__ ed_p, const float4* __restrict__ ea_p,
    const float* __restrict__ ew1_l, const float* __restrict__ eb1_l,
    const float* __restrict__ ew2_l, const float* __restrict__ eb2_l,
    float* __restrict__ agg)
{
    __shared__ __align__(16) short BT[128 * BTS];     // 33792 B (shared by all 8 waves)
    __shared__ __align__(16) short VA[8][16 * BTS];   // 8 x 4224 B (per-wave private)
    __shared__ float s_b2[128];                       // total ~67.9 KB -> 2 blocks/CU

    for (int i = threadIdx.x; i < 128 * 128; i += 512) {
        int k = i >> 7, n = i & 127;
        BT[n * BTS + k] = f2bf(ew2_l[i]);
    }
    if (threadIdx.x < 128) s_b2[threadIdx.x] = eb2_l[threadIdx.x];

    // per-thread column-pair constants (cols 2cp, 2cp+1)
    int cp = threadIdx.x & 63;
    int c0 = cp * 2;
    float wr0  = ew1_l[256 * HD + c0],     wr1  = ew1_l[256 * HD + c0 + 1];
    float wa00 = ew1_l[257 * HD + c0],     wa01 = ew1_l[257 * HD + c0 + 1];
    float wa10 = ew1_l[258 * HD + c0],     wa11 = ew1_l[258 * HD + c0 + 1];
    float wa20 = ew1_l[259 * HD + c0],     wa21 = ew1_l[259 * HD + c0 + 1];
    float wa30 = ew1_l[260 * HD + c0],     wa31 = ew1_l[260 * HD + c0 + 1];
    float b10  = eb1_l[c0],                b11  = eb1_l[c0 + 1];

    int lane = threadIdx.x & 63;
    int wv   = threadIdx.x >> 6;
    int ln15 = lane & 15;
    int quad = lane >> 4;
    short* VAw = &VA[wv][0];
    const unsigned* tb32 = (const unsigned*)tb;
    const unsigned* ub32 = (const unsigned*)ub;
    __syncthreads();   // BT ready (waves never re-sync after this)

    for (int gw = blockIdx.x * 8 + wv; gw < EW16; gw += gridDim.x * 8) {
        // ---- v-phase: 16 edges x cols {c0,c0+1}
        #pragma unroll 8
        for (int i = 0; i < 16; ++i) {
            int p = gw * 16 + i;
            int4   ed = ed_p[p];
            float4 ea = ea_p[p];
            float rad = __int_as_float(ed.z);
            unsigned tw = tb32[ed.x + cp];
            unsigned uw = ub32[ed.y + cp];
            float t0 = __uint_as_float(tw << 16);
            float t1 = __uint_as_float(tw & 0xFFFF0000u);
            float u0 = __uint_as_float(uw << 16);
            float u1 = __uint_as_float(uw & 0xFFFF0000u);
            float base0 = rad * wr0 + ea.x * wa00 + ea.y * wa10 + ea.z * wa20 + ea.w * wa30 + b10;
            float base1 = rad * wr1 + ea.x * wa01 + ea.y * wa11 + ea.z * wa21 + ea.w * wa31 + b11;
            float v0 = silu_f(t0 + u0 + base0);
            float v1 = silu_f(t1 + u1 + base1);
            *(unsigned*)&VAw[i * BTS + c0] = f2bf2u(v0, v1);
        }

        // epilogue edge metadata for this wave's 16 edges (quad owns 4 consecutive)
        int em0 = gw * 16 + quad * 4;
        int4 e0 = ed_p[em0 + 0], e1 = ed_p[em0 + 1], e2 = ed_p[em0 + 2], e3 = ed_p[em0 + 3];
        int   r0 = e0.x, r1 = e1.x, r2 = e2.x, r3 = e3.x;     // scaled by 64
        float mk0 = __int_as_float(e0.w), mk1 = __int_as_float(e1.w);
        float mk2 = __int_as_float(e2.w), mk3 = __int_as_float(e3.w);

        __builtin_amdgcn_wave_barrier();           // keep VA writes above reads
        __builtin_amdgcn_s_waitcnt(0xc07f);        // lgkmcnt(0): VA writes landed

        bf16x8 afr[4];
        #pragma unroll
        for (int kt = 0; kt < 4; ++kt)
            afr[kt] = *(const bf16x8*)&VAw[ln15 * BTS + kt * 32 + quad * 8];

        __builtin_amdgcn_wave_barrier();           // keep reads above next-iter writes

        #pragma unroll
        for (int ct = 0; ct < 8; ++ct) {
            f32x4 acc = {0.f, 0.f, 0.f, 0.f};
            #pragma unroll
            for (int kt = 0; kt < 4; ++kt) {
                bf16x8 bfr = *(const bf16x8*)&BT[(ct * 16 + ln15) * BTS + kt * 32 + quad * 8];
                acc = __builtin_amdgcn_mfma_f32_16x16x32_bf16(afr[kt], bfr, acc, 0, 0, 0);
            }
            int col = ct * 16 + ln15;
            float b2c = s_b2[col];
            float m0 = silu_f(acc[0] + b2c) * mk0;
            float m1 = silu_f(acc[1] + b2c) * mk1;
            float m2 = silu_f(acc[2] + b2c) * mk2;
            float m3 = silu_f(acc[3] + b2c) * mk3;
            // run-length segmented flush (rows CSR-sorted); agg idx = r_scaled*2 + col
            float run = m0;
            int cur = r0;
            if (r1 != cur) { atomicAdd(&agg[cur * 2 + col], run); run = 0.f; cur = r1; }
            run += m1;
            if (r2 != cur) { atomicAdd(&agg[cur * 2 + col], run); run = 0.f; cur = r2; }
            run += m2;
            if (r3 != cur) { atomicAdd(&agg[cur * 2 + col], run); run = 0.f; cur = r3; }
            run += m3;
            atomicAdd(&agg[cur * 2 + col], run);
        }
    }
}

// ---------------- node MLP layer 1 (persistent MFMA) ----------------
__global__ __launch_bounds__(512) void nk1_mfma(
    const float* __restrict__ h, const float* __restrict__ agg,
    const float* __restrict__ h0,
    const float* __restrict__ nw1_l, const float* __restrict__ nb1_l,
    short* __restrict__ qb)
{
    __shared__ __align__(16) short BT[64 * K1S];
    int c0 = blockIdx.y * 64;
    for (int i = threadIdx.x; i < 64 * 288; i += 512) {
        int c = i / 288, k = i - c * 288;
        BT[c * K1S + k] = (k < 267) ? f2bf(nw1_l[k * HD + c0 + c]) : (short)0;
    }
    int wv = threadIdx.x >> 6, lane = threadIdx.x & 63;
    int ln15 = lane & 15, quad = lane >> 4;
    __syncthreads();

    for (int g = blockIdx.x * 8 + wv; g < NG16; g += gridDim.x * 8) {
        int row = g * 16 + ln15;
        const float* hrow = h + row * HD;
        const float* arow = agg + row * HD;
        bf16x8 afr[9];
        #pragma unroll
        for (int kt = 0; kt < 4; ++kt) {
            float4 x0 = *(const float4*)(hrow + kt * 32 + quad * 8);
            float4 x1 = *(const float4*)(hrow + kt * 32 + quad * 8 + 4);
            afr[kt] = pack8(x0, x1);
        }
        #pragma unroll
        for (int kt = 0; kt < 4; ++kt) {
            float4 x0 = *(const float4*)(arow + kt * 32 + quad * 8);
            float4 x1 = *(const float4*)(arow + kt * 32 + quad * 8 + 4);
            afr[4 + kt] = pack8(x0, x1);
        }
        {
            bf16x8 a8 = {0, 0, 0, 0, 0, 0, 0, 0};
            if (quad == 0) {
                #pragma unroll
                for (int jj = 0; jj < 8; ++jj) a8[jj] = f2bf(h0[row * INN + jj]);
            } else if (quad == 1) {
                #pragma unroll
                for (int jj = 0; jj < 3; ++jj) a8[jj] = f2bf(h0[row * INN + 8 + jj]);
            }
            afr[8] = a8;
        }
        #pragma unroll
        for (int ct = 0; ct < 4; ++ct) {
            f32x4 acc = {0.f, 0.f, 0.f, 0.f};
            #pragma unroll
            for (int kt = 0; kt < 9; ++kt) {
                bf16x8 bfr = *(const bf16x8*)&BT[(ct * 16 + ln15) * K1S + kt * 32 + quad * 8];
                acc = __builtin_amdgcn_mfma_f32_16x16x32_bf16(afr[kt], bfr, acc, 0, 0, 0);
            }
            int col = c0 + ct * 16 + ln15;
            float b = nb1_l[col];
            #pragma unroll
            for (int r4 = 0; r4 < 4; ++r4) {
                int orow = g * 16 + quad * 4 + r4;
                qb[orow * HD + col] = f2bf(silu_f(acc[r4] + b));
            }
        }
    }
}

// ---------------- node MLP layer 2 + residual (persistent MFMA) ----------------
__global__ __launch_bounds__(512) void nk2_mfma(
    const short* __restrict__ qb, const float* __restrict__ nw2_l,
    const float* __restrict__ nb2_l, float* __restrict__ h)
{
    __shared__ __align__(16) short BT[128 * BTS];
    for (int i = threadIdx.x; i < 128 * 128; i += 512) {
        int c = i >> 7, k = i & 127;
        BT[c * BTS + k] = f2bf(nw2_l[k * HD + c]);
    }
    int wv = threadIdx.x >> 6, lane = threadIdx.x & 63;
    int ln15 = lane & 15, quad = lane >> 4;
    __syncthreads();

    for (int g = blockIdx.x * 8 + wv; g < NG16; g += gridDim.x * 8) {
        int row = g * 16 + ln15;
        bf16x8 afr[4];
        #pragma unroll
        for (int kt = 0; kt < 4; ++kt)
            afr[kt] = *(const bf16x8*)(qb + row * HD + kt * 32 + quad * 8);

        #pragma unroll
        for (int ct = 0; ct < 8; ++ct) {
            f32x4 acc = {0.f, 0.f, 0.f, 0.f};
            #pragma unroll
            for (int kt = 0; kt < 4; ++kt) {
                bf16x8 bfr = *(const bf16x8*)&BT[(ct * 16 + ln15) * BTS + kt * 32 + quad * 8];
                acc = __builtin_amdgcn_mfma_f32_16x16x32_bf16(afr[kt], bfr, acc, 0, 0, 0);
            }
            int col = ct * 16 + ln15;
            float b = nb2_l[col];
            #pragma unroll
            for (int r4 = 0; r4 < 4; ++r4) {
                int orow = g * 16 + quad * 4 + r4;
                h[orow * HD + col] += acc[r4] + b;
            }
        }
    }
}

extern "C" void kernel_launch(void* const* d_in, const int* in_sizes, int n_in,
                              void* d_out, int out_size, void* d_ws, size_t ws_size,
                              hipStream_t stream)
{
    const float* h0    = (const float*)d_in[0];
    const float* x     = (const float*)d_in[1];
    const int*   ei    = (const int*)d_in[2];
    const float* eattr = (const float*)d_in[3];
    const float* emask = (const float*)d_in[5];
    const float* emb_w = (const float*)d_in[7];
    const float* emb_b = (const float*)d_in[8];
    const float* ew1   = (const float*)d_in[9];
    const float* eb1   = (const float*)d_in[10];
    const float* ew2   = (const float*)d_in[11];
    const float* eb2   = (const float*)d_in[12];
    const float* nw1   = (const float*)d_in[13];
    const float* nb1   = (const float*)d_in[14];
    const float* nw2   = (const float*)d_in[15];
    const float* nb2   = (const float*)d_in[16];

    float* h = (float*)d_out;

    // workspace layout (~80 MB; d_ws >= 256 MiB)
    short*  tb     = (short*)d_ws;                         // NN*HD bf16
    short*  ub     = tb + (size_t)NN * HD;                 // NN*HD bf16
    float*  agg    = (float*)(ub + (size_t)NN * HD);       // NN*HD fp32
    short*  qb     = tb;                                   // alias (tb dead by nk1)
    int*    cnt    = (int*)(agg + (size_t)NN * HD);        // NN
    int*    rowptr = cnt + NN;                             // NN+1
    int*    cursor = rowptr + NN + 1;                      // NN
    int*    eidx   = cursor + NN;                          // NE
    int4*   ed_p   = (int4*)(eidx + NE + 1);               // NE int4 (aligned: offset even)
    float4* ea_p   = (float4*)(ed_p + NE);                 // NE float4

    csr_zero<<<(NN + 255) / 256, 256, 0, stream>>>(cnt);
    csr_hist<<<NE / 256, 256, 0, stream>>>(ei, cnt);
    csr_scan<<<1, 1024, 0, stream>>>(cnt, rowptr, cursor);
    csr_fill<<<NE / 256, 256, 0, stream>>>(ei, cursor, eidx);
    edge_pre<<<NE / 256, 256, 0, stream>>>(ei, eidx, x, eattr, emask, ed_p, ea_p);

    embed_kernel<<<(NN * HD + 255) / 256, 256, 0, stream>>>(h0, emb_w, emb_b, h);

    dim3 gtu(128, 2);
    dim3 gn1(128, 2);
    for (int l = 0; l < NL; ++l) {
        tu_mfma<<<gtu, 512, 0, stream>>>(h, ew1 + l * 261 * HD, tb, ub);
        zero_kernel<<<(NN * HD / 4 + 255) / 256, 256, 0, stream>>>((float4*)agg, NN * HD / 4);
        edge_m_kernel<<<512, 512, 0, stream>>>(tb, ub, ed_p, ea_p,
            ew1 + l * 261 * HD, eb1 + l * HD, ew2 + l * HD * HD, eb2 + l * HD, agg);
        nk1_mfma<<<gn1, 512, 0, stream>>>(h, agg, h0,
            nw1 + l * 267 * HD, nb1 + l * HD, qb);
        nk2_mfma<<<128, 512, 0, stream>>>(qb, nw2 + l * HD * HD, nb2 + l * HD, h);
    }
}

// Round 12
// 1562.388 us; speedup vs baseline: 1.3269x; 1.2609x over previous
//
#include <hip/hip_runtime.h>

#define NN 50000
#define NE 800000
#define HD 128
#define INN 11
#define NL 4
#define NG16 3125        // 16-row node groups
#define BTS 132          // LDS K stride (shorts)
#define K1S 292          // nk1 K stride

typedef __attribute__((ext_vector_type(8))) short bf16x8;
typedef __attribute__((ext_vector_type(4))) float f32x4;

__device__ __forceinline__ float silu_f(float x) {
    return x * __builtin_amdgcn_rcpf(1.0f + __expf(-x));
}

__device__ __forceinline__ short f2bf(float x) {
    unsigned u = __float_as_uint(x);
    return (short)((u + 0x7FFFu + ((u >> 16) & 1u)) >> 16);
}
__device__ __forceinline__ unsigned f2bf2u(float lo, float hi) {
    unsigned a = __float_as_uint(lo), b = __float_as_uint(hi);
    a = (a + 0x7FFFu + ((a >> 16) & 1u)) >> 16;
    b = (b + 0x7FFFu + ((b >> 16) & 1u)) & 0xFFFF0000u;
    return a | b;
}
__device__ __forceinline__ bf16x8 pack8(float4 a, float4 b) {
    bf16x8 r;
    r[0] = f2bf(a.x); r[1] = f2bf(a.y); r[2] = f2bf(a.z); r[3] = f2bf(a.w);
    r[4] = f2bf(b.x); r[5] = f2bf(b.y); r[6] = f2bf(b.z); r[7] = f2bf(b.w);
    return r;
}

// ---------------- embedding ----------------
__global__ __launch_bounds__(256) void embed_kernel(
    const float* __restrict__ h0, const float* __restrict__ w,
    const float* __restrict__ b, float* __restrict__ h)
{
    int idx = blockIdx.x * 256 + threadIdx.x;
    if (idx >= NN * HD) return;
    int n = idx >> 7, j = idx & 127;
    float acc = b[j];
    #pragma unroll
    for (int k = 0; k < INN; ++k)
        acc += h0[n * INN + k] * w[k * HD + j];
    h[idx] = acc;
}

// ---------------- CSR build ----------------
__global__ __launch_bounds__(256) void csr_zero(int* __restrict__ cnt)
{
    int i = blockIdx.x * 256 + threadIdx.x;
    if (i < NN) cnt[i] = 0;
}

__global__ __launch_bounds__(256) void csr_hist(const int* __restrict__ ei, int* __restrict__ cnt)
{
    int e = blockIdx.x * 256 + threadIdx.x;
    atomicAdd(&cnt[ei[e]], 1);
}

__global__ __launch_bounds__(1024) void csr_scan(
    const int* __restrict__ cnt, int* __restrict__ rowptr, int* __restrict__ cursor)
{
    __shared__ int part[1024];
    int t = threadIdx.x;
    int base = t * 49;
    int s = 0;
    for (int i = 0; i < 49; ++i) { int j = base + i; if (j < NN) s += cnt[j]; }
    part[t] = s;
    __syncthreads();
    for (int off = 1; off < 1024; off <<= 1) {
        int v = (t >= off) ? part[t - off] : 0;
        __syncthreads();
        part[t] += v;
        __syncthreads();
    }
    int run = (t == 0) ? 0 : part[t - 1];
    for (int i = 0; i < 49; ++i) {
        int j = base + i;
        if (j < NN) { rowptr[j] = run; cursor[j] = run; run += cnt[j]; }
    }
    if (t == 1023) rowptr[NN] = part[1023];
}

__global__ __launch_bounds__(256) void csr_fill(
    const int* __restrict__ ei, int* __restrict__ cursor, int* __restrict__ eidx)
{
    int e = blockIdx.x * 256 + threadIdx.x;
    int r = ei[e];
    int p = atomicAdd(&cursor[r], 1);
    eidx[p] = e;
}

// ---------------- per-edge data, CSR order; ed = {r*64, c*64, rad, mask} ----------------
__global__ __launch_bounds__(256) void edge_pre(
    const int* __restrict__ ei, const int* __restrict__ eidx,
    const float* __restrict__ x, const float* __restrict__ eattr,
    const float* __restrict__ emask,
    int4* __restrict__ ed_p, float4* __restrict__ ea_p)
{
    int p = blockIdx.x * 256 + threadIdx.x;
    int e = eidx[p];
    int r = ei[e], c = ei[NE + e];
    float dx = x[3 * r]     - x[3 * c];
    float dy = x[3 * r + 1] - x[3 * c + 1];
    float dz = x[3 * r + 2] - x[3 * c + 2];
    float rad = dx * dx + dy * dy + dz * dz;
    ed_p[p] = make_int4(r * 64, c * 64, __float_as_int(rad), __float_as_int(emask[e]));
    ea_p[p] = ((const float4*)eattr)[e];
}

// ---------------- t|u = h @ ew1 halves (persistent MFMA, bf16 out) ----------------
__global__ __launch_bounds__(512) void tu_mfma(
    const float* __restrict__ h, const float* __restrict__ ew1_l,
    short* __restrict__ tb, short* __restrict__ ub)
{
    __shared__ __align__(16) short BT[128 * BTS];
    const float* wsrc = ew1_l + (blockIdx.y ? 128 * HD : 0);
    short* outp = blockIdx.y ? ub : tb;
    for (int i = threadIdx.x; i < 128 * 128; i += 512) {
        int c = i >> 7, k = i & 127;
        BT[c * BTS + k] = f2bf(wsrc[k * HD + c]);
    }
    int wv = threadIdx.x >> 6, lane = threadIdx.x & 63;
    int ln15 = lane & 15, quad = lane >> 4;
    __syncthreads();

    for (int g = blockIdx.x * 8 + wv; g < NG16; g += gridDim.x * 8) {
        int row = g * 16 + ln15;
        const float* hrow = h + row * HD;
        bf16x8 afr[4];
        #pragma unroll
        for (int kt = 0; kt < 4; ++kt) {
            float4 x0 = *(const float4*)(hrow + kt * 32 + quad * 8);
            float4 x1 = *(const float4*)(hrow + kt * 32 + quad * 8 + 4);
            afr[kt] = pack8(x0, x1);
        }
        #pragma unroll
        for (int ct = 0; ct < 8; ++ct) {
            f32x4 acc = {0.f, 0.f, 0.f, 0.f};
            #pragma unroll
            for (int kt = 0; kt < 4; ++kt) {
                bf16x8 bfr = *(const bf16x8*)&BT[(ct * 16 + ln15) * BTS + kt * 32 + quad * 8];
                acc = __builtin_amdgcn_mfma_f32_16x16x32_bf16(afr[kt], bfr, acc, 0, 0, 0);
            }
            int col = ct * 16 + ln15;
            #pragma unroll
            for (int r4 = 0; r4 < 4; ++r4) {
                int orow = g * 16 + quad * 4 + r4;
                outp[orow * HD + col] = f2bf(acc[r4]);
            }
        }
    }
}

// ---------------- node-aligned fused edge model: one node per wave, NO atomics ----------------
// Wave processes all edges of node n in 16-edge tiles; t-row loaded once; per-tile
// m-rows reduced in-wave; final agg[n] written with plain stores.
__global__ __launch_bounds__(512) void edge_m_kernel(
    const short* __restrict__ tb, const short* __restrict__ ub,
    const int4* __restrict__ ed_p, const float4* __restrict__ ea_p,
    const int* __restrict__ rowptr,
    const float* __restrict__ ew1_l, const float* __restrict__ eb1_l,
    const float* __restrict__ ew2_l, const float* __restrict__ eb2_l,
    float* __restrict__ agg)
{
    __shared__ __align__(16) short BT[128 * BTS];     // 33792 B (shared by 8 waves)
    __shared__ __align__(16) short VA[8][16 * BTS];   // 8 x 4224 B (per-wave private)
    __shared__ float s_b2[128];                       // ~68 KB -> 2 blocks/CU

    for (int i = threadIdx.x; i < 128 * 128; i += 512) {
        int k = i >> 7, n = i & 127;
        BT[n * BTS + k] = f2bf(ew2_l[i]);
    }
    if (threadIdx.x < 128) s_b2[threadIdx.x] = eb2_l[threadIdx.x];

    // per-thread column-pair constants (cols 2cp, 2cp+1)
    int cp = threadIdx.x & 63;
    int c0 = cp * 2;
    float wr0  = ew1_l[256 * HD + c0],     wr1  = ew1_l[256 * HD + c0 + 1];
    float wa00 = ew1_l[257 * HD + c0],     wa01 = ew1_l[257 * HD + c0 + 1];
    float wa10 = ew1_l[258 * HD + c0],     wa11 = ew1_l[258 * HD + c0 + 1];
    float wa20 = ew1_l[259 * HD + c0],     wa21 = ew1_l[259 * HD + c0 + 1];
    float wa30 = ew1_l[260 * HD + c0],     wa31 = ew1_l[260 * HD + c0 + 1];
    float b10  = eb1_l[c0],                b11  = eb1_l[c0 + 1];

    int lane = threadIdx.x & 63;
    int wv   = threadIdx.x >> 6;
    int ln15 = lane & 15;
    int quad = lane >> 4;
    short* VAw = &VA[wv][0];
    const unsigned* tb32 = (const unsigned*)tb;
    const unsigned* ub32 = (const unsigned*)ub;
    __syncthreads();   // BT ready (no further block syncs)

    for (int n = blockIdx.x * 8 + wv; n < NN; n += gridDim.x * 8) {
        int s = rowptr[n], e = rowptr[n + 1];
        unsigned tw = tb32[n * 64 + cp];       // this node's t row: loaded ONCE
        float t0 = __uint_as_float(tw << 16);
        float t1 = __uint_as_float(tw & 0xFFFF0000u);

        float sums[8];
        #pragma unroll
        for (int ct = 0; ct < 8; ++ct) sums[ct] = 0.f;

        for (int base = s; base < e; base += 16) {
            // ---- v-phase: tile edges base..base+15 (pad rows -> 0)
            #pragma unroll 4
            for (int i = 0; i < 16; ++i) {
                int p = base + i;
                unsigned out = 0u;
                if (p < e) {
                    int4   ed = ed_p[p];
                    float4 ea = ea_p[p];
                    float rad = __int_as_float(ed.z);
                    unsigned uw = ub32[ed.y + cp];
                    float u0 = __uint_as_float(uw << 16);
                    float u1 = __uint_as_float(uw & 0xFFFF0000u);
                    float base0 = rad * wr0 + ea.x * wa00 + ea.y * wa10 + ea.z * wa20 + ea.w * wa30 + b10;
                    float base1 = rad * wr1 + ea.x * wa01 + ea.y * wa11 + ea.z * wa21 + ea.w * wa31 + b11;
                    out = f2bf2u(silu_f(t0 + u0 + base0), silu_f(t1 + u1 + base1));
                }
                *(unsigned*)&VAw[i * BTS + c0] = out;
            }

            // row masks for this lane's 4 rows (pad -> 0)
            int pr = base + quad * 4;
            float mk0 = (pr + 0 < e) ? __int_as_float(ed_p[pr + 0].w) : 0.f;
            float mk1 = (pr + 1 < e) ? __int_as_float(ed_p[pr + 1].w) : 0.f;
            float mk2 = (pr + 2 < e) ? __int_as_float(ed_p[pr + 2].w) : 0.f;
            float mk3 = (pr + 3 < e) ? __int_as_float(ed_p[pr + 3].w) : 0.f;

            __builtin_amdgcn_wave_barrier();       // VA writes above reads
            __builtin_amdgcn_s_waitcnt(0xc07f);    // lgkmcnt(0)

            bf16x8 afr[4];
            #pragma unroll
            for (int kt = 0; kt < 4; ++kt)
                afr[kt] = *(const bf16x8*)&VAw[ln15 * BTS + kt * 32 + quad * 8];

            __builtin_amdgcn_wave_barrier();       // reads above next-iter writes

            #pragma unroll
            for (int ct = 0; ct < 8; ++ct) {
                f32x4 acc = {0.f, 0.f, 0.f, 0.f};
                #pragma unroll
                for (int kt = 0; kt < 4; ++kt) {
                    bf16x8 bfr = *(const bf16x8*)&BT[(ct * 16 + ln15) * BTS + kt * 32 + quad * 8];
                    acc = __builtin_amdgcn_mfma_f32_16x16x32_bf16(afr[kt], bfr, acc, 0, 0, 0);
                }
                float b2c = s_b2[ct * 16 + ln15];
                sums[ct] += silu_f(acc[0] + b2c) * mk0 + silu_f(acc[1] + b2c) * mk1
                          + silu_f(acc[2] + b2c) * mk2 + silu_f(acc[3] + b2c) * mk3;
            }
        }

        // cross-quad reduction: lanes {ln15, +16, +32, +48} hold partials for same col
        #pragma unroll
        for (int ct = 0; ct < 8; ++ct) {
            float v = sums[ct];
            v += __shfl_xor(v, 16, 64);
            v += __shfl_xor(v, 32, 64);
            sums[ct] = v;
        }
        // each lane stores 2 cols (constant-index select tree; no atomics)
        float vA = (quad & 2) ? ((quad & 1) ? sums[6] : sums[4])
                              : ((quad & 1) ? sums[2] : sums[0]);
        float vB = (quad & 2) ? ((quad & 1) ? sums[7] : sums[5])
                              : ((quad & 1) ? sums[3] : sums[1]);
        int colA = quad * 32 + ln15;
        agg[n * HD + colA]      = vA;
        agg[n * HD + colA + 16] = vB;
    }
}

// ---------------- node MLP layer 1 (persistent MFMA) ----------------
__global__ __launch_bounds__(512) void nk1_mfma(
    const float* __restrict__ h, const float* __restrict__ agg,
    const float* __restrict__ h0,
    const float* __restrict__ nw1_l, const float* __restrict__ nb1_l,
    short* __restrict__ qb)
{
    __shared__ __align__(16) short BT[64 * K1S];
    int c0 = blockIdx.y * 64;
    for (int i = threadIdx.x; i < 64 * 288; i += 512) {
        int c = i / 288, k = i - c * 288;
        BT[c * K1S + k] = (k < 267) ? f2bf(nw1_l[k * HD + c0 + c]) : (short)0;
    }
    int wv = threadIdx.x >> 6, lane = threadIdx.x & 63;
    int ln15 = lane & 15, quad = lane >> 4;
    __syncthreads();

    for (int g = blockIdx.x * 8 + wv; g < NG16; g += gridDim.x * 8) {
        int row = g * 16 + ln15;
        const float* hrow = h + row * HD;
        const float* arow = agg + row * HD;
        bf16x8 afr[9];
        #pragma unroll
        for (int kt = 0; kt < 4; ++kt) {
            float4 x0 = *(const float4*)(hrow + kt * 32 + quad * 8);
            float4 x1 = *(const float4*)(hrow + kt * 32 + quad * 8 + 4);
            afr[kt] = pack8(x0, x1);
        }
        #pragma unroll
        for (int kt = 0; kt < 4; ++kt) {
            float4 x0 = *(const float4*)(arow + kt * 32 + quad * 8);
            float4 x1 = *(const float4*)(arow + kt * 32 + quad * 8 + 4);
            afr[4 + kt] = pack8(x0, x1);
        }
        {
            bf16x8 a8 = {0, 0, 0, 0, 0, 0, 0, 0};
            if (quad == 0) {
                #pragma unroll
                for (int jj = 0; jj < 8; ++jj) a8[jj] = f2bf(h0[row * INN + jj]);
            } else if (quad == 1) {
                #pragma unroll
                for (int jj = 0; jj < 3; ++jj) a8[jj] = f2bf(h0[row * INN + 8 + jj]);
            }
            afr[8] = a8;
        }
        #pragma unroll
        for (int ct = 0; ct < 4; ++ct) {
            f32x4 acc = {0.f, 0.f, 0.f, 0.f};
            #pragma unroll
            for (int kt = 0; kt < 9; ++kt) {
                bf16x8 bfr = *(const bf16x8*)&BT[(ct * 16 + ln15) * K1S + kt * 32 + quad * 8];
                acc = __builtin_amdgcn_mfma_f32_16x16x32_bf16(afr[kt], bfr, acc, 0, 0, 0);
            }
            int col = c0 + ct * 16 + ln15;
            float b = nb1_l[col];
            #pragma unroll
            for (int r4 = 0; r4 < 4; ++r4) {
                int orow = g * 16 + quad * 4 + r4;
                qb[orow * HD + col] = f2bf(silu_f(acc[r4] + b));
            }
        }
    }
}

// ---------------- node MLP layer 2 + residual (persistent MFMA) ----------------
__global__ __launch_bounds__(512) void nk2_mfma(
    const short* __restrict__ qb, const float* __restrict__ nw2_l,
    const float* __restrict__ nb2_l, float* __restrict__ h)
{
    __shared__ __align__(16) short BT[128 * BTS];
    for (int i = threadIdx.x; i < 128 * 128; i += 512) {
        int c = i >> 7, k = i & 127;
        BT[c * BTS + k] = f2bf(nw2_l[k * HD + c]);
    }
    int wv = threadIdx.x >> 6, lane = threadIdx.x & 63;
    int ln15 = lane & 15, quad = lane >> 4;
    __syncthreads();

    for (int g = blockIdx.x * 8 + wv; g < NG16; g += gridDim.x * 8) {
        int row = g * 16 + ln15;
        bf16x8 afr[4];
        #pragma unroll
        for (int kt = 0; kt < 4; ++kt)
            afr[kt] = *(const bf16x8*)(qb + row * HD + kt * 32 + quad * 8);

        #pragma unroll
        for (int ct = 0; ct < 8; ++ct) {
            f32x4 acc = {0.f, 0.f, 0.f, 0.f};
            #pragma unroll
            for (int kt = 0; kt < 4; ++kt) {
                bf16x8 bfr = *(const bf16x8*)&BT[(ct * 16 + ln15) * BTS + kt * 32 + quad * 8];
                acc = __builtin_amdgcn_mfma_f32_16x16x32_bf16(afr[kt], bfr, acc, 0, 0, 0);
            }
            int col = ct * 16 + ln15;
            float b = nb2_l[col];
            #pragma unroll
            for (int r4 = 0; r4 < 4; ++r4) {
                int orow = g * 16 + quad * 4 + r4;
                h[orow * HD + col] += acc[r4] + b;
            }
        }
    }
}

extern "C" void kernel_launch(void* const* d_in, const int* in_sizes, int n_in,
                              void* d_out, int out_size, void* d_ws, size_t ws_size,
                              hipStream_t stream)
{
    const float* h0    = (const float*)d_in[0];
    const float* x     = (const float*)d_in[1];
    const int*   ei    = (const int*)d_in[2];
    const float* eattr = (const float*)d_in[3];
    const float* emask = (const float*)d_in[5];
    const float* emb_w = (const float*)d_in[7];
    const float* emb_b = (const float*)d_in[8];
    const float* ew1   = (const float*)d_in[9];
    const float* eb1   = (const float*)d_in[10];
    const float* ew2   = (const float*)d_in[11];
    const float* eb2   = (const float*)d_in[12];
    const float* nw1   = (const float*)d_in[13];
    const float* nb1   = (const float*)d_in[14];
    const float* nw2   = (const float*)d_in[15];
    const float* nb2   = (const float*)d_in[16];

    float* h = (float*)d_out;

    // workspace layout (~80 MB; d_ws >= 256 MiB)
    short*  tb     = (short*)d_ws;                         // NN*HD bf16
    short*  ub     = tb + (size_t)NN * HD;                 // NN*HD bf16
    float*  agg    = (float*)(ub + (size_t)NN * HD);       // NN*HD fp32
    short*  qb     = tb;                                   // alias (tb dead by nk1)
    int*    cnt    = (int*)(agg + (size_t)NN * HD);        // NN
    int*    rowptr = cnt + NN;                             // NN+1
    int*    cursor = rowptr + NN + 1;                      // NN
    int*    eidx   = cursor + NN;                          // NE
    int4*   ed_p   = (int4*)(eidx + NE + 1);               // NE int4
    float4* ea_p   = (float4*)(ed_p + NE);                 // NE float4

    csr_zero<<<(NN + 255) / 256, 256, 0, stream>>>(cnt);
    csr_hist<<<NE / 256, 256, 0, stream>>>(ei, cnt);
    csr_scan<<<1, 1024, 0, stream>>>(cnt, rowptr, cursor);
    csr_fill<<<NE / 256, 256, 0, stream>>>(ei, cursor, eidx);
    edge_pre<<<NE / 256, 256, 0, stream>>>(ei, eidx, x, eattr, emask, ed_p, ea_p);

    embed_kernel<<<(NN * HD + 255) / 256, 256, 0, stream>>>(h0, emb_w, emb_b, h);

    dim3 gtu(128, 2);
    dim3 gn1(128, 2);
    for (int l = 0; l < NL; ++l) {
        tu_mfma<<<gtu, 512, 0, stream>>>(h, ew1 + l * 261 * HD, tb, ub);
        edge_m_kernel<<<512, 512, 0, stream>>>(tb, ub, ed_p, ea_p, rowptr,
            ew1 + l * 261 * HD, eb1 + l * HD, ew2 + l * HD * HD, eb2 + l * HD, agg);
        nk1_mfma<<<gn1, 512, 0, stream>>>(h, agg, h0,
            nw1 + l * 267 * HD, nb1 + l * HD, qb);
        nk2_mfma<<<128, 512, 0, stream>>>(qb, nw2 + l * HD * HD, nb2 + l * HD, h);
    }
}